// Round 4
// baseline (46.743 us; speedup 1.0000x reference)
//
#include <hip/hip_runtime.h>

// Blur+downsample: (32,512,512,3) f32 NHWC, 2x2 depthwise kernel, stride 2, SAME.
// SAME pad is 0 (512 even, k=2, s=2) -> non-overlapping weighted 2x2 pool:
// out[b,oh,ow,c] = k00*x[2oh,2ow,c] + k01*x[2oh,2ow+1,c]
//                + k10*x[2oh+1,2ow,c] + k11*x[2oh+1,2ow+1,c]
//
// R3: nontemporal A/B vs R1 baseline. __builtin_nontemporal_* requires a
// native clang vector type (not HIP_vector_type), so use ext_vector_type(4).

typedef float f32x4 __attribute__((ext_vector_type(4)));

#define ROWF 1536          // floats per input row (512*3)
#define NBLOCKS 2048       // 524288 threads * 12 floats = 6291456 out floats

__global__ __launch_bounds__(256) void blur_ds_kernel(
    const float* __restrict__ x, const float* __restrict__ kern,
    float* __restrict__ out) {
  const int g = blockIdx.x * 256 + threadIdx.x;
  const int r = g >> 6;     // combined (b*256 + oh) output-row id, 0..8191
  const int lane = g & 63;  // 64 threads per output row, 4 pixels each

  const float k00 = kern[0];
  const float k01 = kern[1];
  const float k10 = kern[2];
  const float k11 = kern[3];

  // input rows 2*oh, 2*oh+1 of image b == rows 2r, 2r+1 of the flat row array
  const f32x4* s0 = (const f32x4*)(x + (size_t)r * (2 * ROWF) + lane * 24);
  const f32x4* s1 = s0 + (ROWF / 4);

  float af[24], bf[24];  // all indices compile-time after unroll -> registers
#pragma unroll
  for (int j = 0; j < 6; ++j) {
    const f32x4 v = __builtin_nontemporal_load(&s0[j]);
    af[4 * j + 0] = v.x; af[4 * j + 1] = v.y;
    af[4 * j + 2] = v.z; af[4 * j + 3] = v.w;
  }
#pragma unroll
  for (int j = 0; j < 6; ++j) {
    const f32x4 v = __builtin_nontemporal_load(&s1[j]);
    bf[4 * j + 0] = v.x; bf[4 * j + 1] = v.y;
    bf[4 * j + 2] = v.z; bf[4 * j + 3] = v.w;
  }

  float of[12];
#pragma unroll
  for (int p = 0; p < 4; ++p) {
#pragma unroll
    for (int c = 0; c < 3; ++c) {
      const int gi = 6 * p + c;
      of[3 * p + c] = k00 * af[gi] + k01 * af[gi + 3] +
                      k10 * bf[gi] + k11 * bf[gi + 3];
    }
  }

  f32x4* o4 = (f32x4*)(out + (size_t)g * 12);  // 48B/thread, 16B-aligned
  f32x4 o0 = {of[0], of[1], of[2], of[3]};
  f32x4 o1 = {of[4], of[5], of[6], of[7]};
  f32x4 o2 = {of[8], of[9], of[10], of[11]};
  __builtin_nontemporal_store(o0, &o4[0]);
  __builtin_nontemporal_store(o1, &o4[1]);
  __builtin_nontemporal_store(o2, &o4[2]);
}

extern "C" void kernel_launch(void* const* d_in, const int* in_sizes, int n_in,
                              void* d_out, int out_size, void* d_ws,
                              size_t ws_size, hipStream_t stream) {
  const float* x = (const float*)d_in[0];
  const float* kern = (const float*)d_in[1];
  float* out = (float*)d_out;

  blur_ds_kernel<<<NBLOCKS, 256, 0, stream>>>(x, kern, out);
}

// Round 5
// 26.635 us; speedup vs baseline: 1.7549x; 1.7549x over previous
//
#include <hip/hip_runtime.h>

// Blur+downsample: (32,512,512,3) f32 NHWC, 2x2 depthwise kernel, stride 2, SAME.
// SAME pad is 0 (512 even, k=2, s=2) -> non-overlapping weighted 2x2 pool:
// out[b,oh,ow,c] = k00*x[2oh,2ow,c] + k01*x[2oh,2ow+1,c]
//                + k10*x[2oh+1,2ow,c] + k11*x[2oh+1,2ow+1,c]
//
// R4 lesson: nt LOADS amplified HBM reads ~2x (96B-stride pattern needs L1
// line merging across the 6 loads/thread). This round: plain cached loads,
// nt ONLY on stores (each output byte written once, never re-read).

typedef float f32x4 __attribute__((ext_vector_type(4)));

#define ROWF 1536          // floats per input row (512*3)
#define NBLOCKS 2048       // 524288 threads * 12 floats = 6291456 out floats

__global__ __launch_bounds__(256) void blur_ds_kernel(
    const float* __restrict__ x, const float* __restrict__ kern,
    float* __restrict__ out) {
  const int g = blockIdx.x * 256 + threadIdx.x;
  const int r = g >> 6;     // combined (b*256 + oh) output-row id, 0..8191
  const int lane = g & 63;  // 64 threads per output row, 4 pixels each

  const float k00 = kern[0];
  const float k01 = kern[1];
  const float k10 = kern[2];
  const float k11 = kern[3];

  // input rows 2*oh, 2*oh+1 of image b == rows 2r, 2r+1 of the flat row array
  const float4* s0 = (const float4*)(x + (size_t)r * (2 * ROWF) + lane * 24);
  const float4* s1 = s0 + (ROWF / 4);

  float af[24], bf[24];  // all indices compile-time after unroll -> registers
#pragma unroll
  for (int j = 0; j < 6; ++j) {
    const float4 v = s0[j];
    af[4 * j + 0] = v.x; af[4 * j + 1] = v.y;
    af[4 * j + 2] = v.z; af[4 * j + 3] = v.w;
  }
#pragma unroll
  for (int j = 0; j < 6; ++j) {
    const float4 v = s1[j];
    bf[4 * j + 0] = v.x; bf[4 * j + 1] = v.y;
    bf[4 * j + 2] = v.z; bf[4 * j + 3] = v.w;
  }

  float of[12];
#pragma unroll
  for (int p = 0; p < 4; ++p) {
#pragma unroll
    for (int c = 0; c < 3; ++c) {
      const int gi = 6 * p + c;
      of[3 * p + c] = k00 * af[gi] + k01 * af[gi + 3] +
                      k10 * bf[gi] + k11 * bf[gi + 3];
    }
  }

  f32x4* o4 = (f32x4*)(out + (size_t)g * 12);  // 48B/thread, 16B-aligned
  f32x4 o0 = {of[0], of[1], of[2], of[3]};
  f32x4 o1 = {of[4], of[5], of[6], of[7]};
  f32x4 o2 = {of[8], of[9], of[10], of[11]};
  __builtin_nontemporal_store(o0, &o4[0]);
  __builtin_nontemporal_store(o1, &o4[1]);
  __builtin_nontemporal_store(o2, &o4[2]);
}

extern "C" void kernel_launch(void* const* d_in, const int* in_sizes, int n_in,
                              void* d_out, int out_size, void* d_ws,
                              size_t ws_size, hipStream_t stream) {
  const float* x = (const float*)d_in[0];
  const float* kern = (const float*)d_in[1];
  float* out = (float*)d_out;

  blur_ds_kernel<<<NBLOCKS, 256, 0, stream>>>(x, kern, out);
}

// Round 6
// 23.859 us; speedup vs baseline: 1.9591x; 1.1164x over previous
//
#include <hip/hip_runtime.h>

// Blur+downsample: (32,512,512,3) f32 NHWC, 2x2 depthwise kernel, stride 2, SAME.
// SAME pad is 0 here (512 even, k=2, s=2) -> non-overlapping weighted 2x2 pool.
// out[b,oh,ow,c] = k00*x[2oh,2ow] + k01*x[2oh,2ow+1] + k10*x[2oh+1,2ow] + k11*x[2oh+1,2ow+1]
//
// FINAL (revert to R1 = best measured, 23.9 us):
//   R1 LDS-staged, plain loads/stores:  23.9 us  <-- this kernel
//   R2 direct-register, plain:          24.1 us
//   R4 nontemporal loads:               46.7 us  (defeats L1 line merging, ~2x read amplification)
//   R5 nontemporal stores:              26.6 us  (bypasses default write path, -10%)
// 125.8 MB minimum traffic @ 24 us = 5.25 TB/s (84% of 6.29 TB/s copy ceiling);
// memory-bound at the mixed-stream limit.

#define BATCH 32
#define H 512
#define W 512
#define C 3
#define OH (H / 2)
#define OW (W / 2)
#define ROWF (W * C)    // 1536 floats per input row
#define OROWF (OW * C)  // 768 floats per output row

__global__ __launch_bounds__(256) void blur_ds_kernel(
    const float* __restrict__ x, const float* __restrict__ kern,
    float* __restrict__ out) {
  // One block per (b, oh). The two input rows it needs are contiguous:
  // rows 2*oh and 2*oh+1 of image b -> one 3072-float (12 KB) span.
  __shared__ float lds[2 * ROWF];  // 12 KB

  const int blk = blockIdx.x;  // b*OH + oh
  const int t = threadIdx.x;

  const float k00 = kern[0];
  const float k01 = kern[1];
  const float k10 = kern[2];
  const float k11 = kern[3];

  const float* src = x + (size_t)blk * (2 * ROWF);  // 16B-aligned

  // Stage 3072 floats = 768 float4 with fully coalesced loads (3 per thread).
  const float4* s4 = (const float4*)src;
  float4* l4 = (float4*)lds;
#pragma unroll
  for (int i = 0; i < 3; ++i) {
    l4[t + i * 256] = s4[t + i * 256];
  }
  __syncthreads();

  float* orow = out + (size_t)blk * OROWF;

  // 768 output floats per row, 3 per thread; output flat index f -> (ow, c):
  // ow = f/3, c = f%3; input element within row g = 6*ow + c.
  // LDS read stride across lanes ~2 words -> 2-way bank aliasing (free).
#pragma unroll
  for (int i = 0; i < 3; ++i) {
    const int f = t + i * 256;
    const int ow = f / 3;
    const int c = f - 3 * ow;
    const int g = 6 * ow + c;
    const float v = k00 * lds[g] + k01 * lds[g + 3] + k10 * lds[ROWF + g] +
                    k11 * lds[ROWF + g + 3];
    orow[f] = v;  // stride-1 across lanes -> fully coalesced stores
  }
}

extern "C" void kernel_launch(void* const* d_in, const int* in_sizes, int n_in,
                              void* d_out, int out_size, void* d_ws,
                              size_t ws_size, hipStream_t stream) {
  const float* x = (const float*)d_in[0];
  const float* kern = (const float*)d_in[1];
  float* out = (float*)d_out;

  const int nblocks = BATCH * OH;  // 8192
  blur_ds_kernel<<<nblocks, 256, 0, stream>>>(x, kern, out);
}